// Round 1
// baseline (733.591 us; speedup 1.0000x reference)
//
#include <hip/hip_runtime.h>
#include <cstdint>

// QuIP#-style quantized linear on MI355X:
//   x = FWHT(input*SU) * Wscale/64  (bf16)
//   W = bf16(cb[Qidxs])             (bf16, [4096 out][4096 in], K-contiguous)
//   C = x @ W^T                     (m97-structure MFMA GEMM, fp32 out)
//   out = FWHT(C)/64 * SV + bias    (in-place on d_out)

using bf16x8 = __attribute__((ext_vector_type(8))) __bf16;
using f32x4  = __attribute__((ext_vector_type(4))) float;

__device__ __forceinline__ unsigned short f2bf(float f) {
    unsigned int u = __float_as_uint(f);
    unsigned int r = (u + 0x7fffu + ((u >> 16) & 1u)) >> 16;
    return (unsigned short)r;
}

// ---------------- FWHT over 4096 floats in LDS, 256 threads ----------------
__device__ __forceinline__ void fwht4096(float* row, int t) {
    for (int h = 1; h < 4096; h <<= 1) {
#pragma unroll
        for (int q = 0; q < 8; ++q) {
            int p = t + (q << 8);
            int i = ((p & ~(h - 1)) << 1) | (p & (h - 1));
            float a = row[i];
            float b = row[i + h];
            row[i]     = a + b;
            row[i + h] = a - b;
        }
        __syncthreads();
    }
}

// ---------------- kernel 1: input scale + FWHT -> bf16 X ----------------
__global__ __launch_bounds__(256) void fwht_in_kernel(const float* __restrict__ inp,
                                                      const float* __restrict__ SU,
                                                      const float* __restrict__ wscale,
                                                      unsigned short* __restrict__ X) {
    __shared__ float row[4096];
    const int t = threadIdx.x;
    const size_t base = (size_t)blockIdx.x * 4096;
    const float4* in4 = (const float4*)(inp + base);
    const float4* su4 = (const float4*)SU;
#pragma unroll
    for (int j = 0; j < 4; ++j) {
        int v = t + (j << 8);
        float4 x = in4[v];
        float4 s = su4[v];
        x.x *= s.x; x.y *= s.y; x.z *= s.z; x.w *= s.w;
        ((float4*)row)[v] = x;
    }
    __syncthreads();
    fwht4096(row, t);
    const float sc = wscale[0] * 0.015625f;  // /sqrt(4096)
#pragma unroll
    for (int j = 0; j < 2; ++j) {
        int i0 = (t << 3) + (j << 11);
        union { unsigned short us[8]; uint4 v4; } pk;
#pragma unroll
        for (int c = 0; c < 8; ++c) pk.us[c] = f2bf(row[i0 + c] * sc);
        *(uint4*)(X + base + i0) = pk.v4;
    }
}

// ---------------- kernel 2: codebook decode -> bf16 W ----------------
__global__ __launch_bounds__(256) void decode_kernel(const int* __restrict__ Qidxs,
                                                     const float* __restrict__ cb,
                                                     unsigned short* __restrict__ Wb) {
    __shared__ float4 cbs[256];
    const int t = threadIdx.x;
    cbs[t] = ((const float4*)cb)[t];
    __syncthreads();
    const size_t o = blockIdx.x;
    const int* q = Qidxs + o * 1024;
    ushort4* wrow = (ushort4*)(Wb + o * 4096);
#pragma unroll
    for (int jj = 0; jj < 4; ++jj) {
        int j = t + (jj << 8);
        int idx = q[j];
        float4 v = cbs[idx];
        ushort4 w4;
        w4.x = f2bf(v.x); w4.y = f2bf(v.y); w4.z = f2bf(v.z); w4.w = f2bf(v.w);
        wrow[j] = w4;
    }
}

// ---------------- kernel 3: bf16 GEMM C = X @ W^T (m97 structure) ----------------
// X: [8192][4096] bf16, Wb: [4096][4096] bf16 (both K-contiguous), C: fp32
__global__ __launch_bounds__(256) void gemm_kernel(const unsigned short* __restrict__ X,
                                                   const unsigned short* __restrict__ Wb,
                                                   float* __restrict__ C) {
    __shared__ unsigned short As[128 * 64];
    __shared__ unsigned short Bs[128 * 64];

    const int tid  = threadIdx.x;
    const int lane = tid & 63;
    const int w    = tid >> 6;
    const int wr   = (w >> 1) * 64;
    const int wc   = (w & 1) * 64;
    const int lr   = lane & 15;
    const int kg   = (lane >> 4) * 8;

    // XCD-bijective swizzle (2048 blocks, 2048 % 8 == 0)
    const int bid  = blockIdx.x;
    const int swz  = (bid & 7) * 256 + (bid >> 3);
    const int trow = (swz >> 5) * 128;   // 64 row tiles
    const int tcol = (swz & 31) * 128;   // 32 col tiles

    const int r_a = tid >> 3;        // 0..31: row within 32-row chunk
    const int kc  = (tid & 7) * 8;   // k element offset within BK=64

    f32x4 acc[4][4] = {};

    for (int kt = 0; kt < 4096; kt += 64) {
#pragma unroll
        for (int it = 0; it < 4; ++it) {
            int r = it * 32 + r_a;
            const unsigned short* srcA = X  + (size_t)(trow + r) * 4096 + kt + kc;
            const unsigned short* srcB = Wb + (size_t)(tcol + r) * 4096 + kt + kc;
            __builtin_amdgcn_global_load_lds(
                (const __attribute__((address_space(1))) unsigned int*)srcA,
                (__attribute__((address_space(3))) unsigned int*)((char*)As + it * 4096 + tid * 16),
                16, 0, 0);
            __builtin_amdgcn_global_load_lds(
                (const __attribute__((address_space(1))) unsigned int*)srcB,
                (__attribute__((address_space(3))) unsigned int*)((char*)Bs + it * 4096 + tid * 16),
                16, 0, 0);
        }
        __syncthreads();

#pragma unroll
        for (int kk = 0; kk < 64; kk += 32) {
            bf16x8 af[4], bfr[4];
#pragma unroll
            for (int m = 0; m < 4; ++m)
                af[m] = *(const bf16x8*)(As + (wr + m * 16 + lr) * 64 + kk + kg);
#pragma unroll
            for (int n = 0; n < 4; ++n)
                bfr[n] = *(const bf16x8*)(Bs + (wc + n * 16 + lr) * 64 + kk + kg);
#pragma unroll
            for (int m = 0; m < 4; ++m)
#pragma unroll
                for (int n = 0; n < 4; ++n)
                    acc[m][n] = __builtin_amdgcn_mfma_f32_16x16x32_bf16(af[m], bfr[n], acc[m][n], 0, 0, 0);
        }
        __syncthreads();
    }

    // epilogue: C/D layout col=lane&15, row=(lane>>4)*4+reg
#pragma unroll
    for (int m = 0; m < 4; ++m) {
        int row0 = trow + wr + m * 16 + (lane >> 4) * 4;
#pragma unroll
        for (int n = 0; n < 4; ++n) {
            int col = tcol + wc + n * 16 + lr;
#pragma unroll
            for (int r = 0; r < 4; ++r)
                C[(size_t)(row0 + r) * 4096 + col] = acc[m][n][r];
        }
    }
}

// ---------------- kernel 4: output FWHT + SV scale + bias (in place) ----------------
__global__ __launch_bounds__(256) void fwht_out_kernel(float* __restrict__ out,
                                                       const float* __restrict__ SV,
                                                       const float* __restrict__ bias) {
    __shared__ float row[4096];
    const int t = threadIdx.x;
    const size_t base = (size_t)blockIdx.x * 4096;
    float4* o4 = (float4*)(out + base);
#pragma unroll
    for (int j = 0; j < 4; ++j) {
        int v = t + (j << 8);
        ((float4*)row)[v] = o4[v];
    }
    __syncthreads();
    fwht4096(row, t);
    const float4* sv4 = (const float4*)SV;
    const float4* b4  = (const float4*)bias;
#pragma unroll
    for (int j = 0; j < 4; ++j) {
        int v = t + (j << 8);
        float4 x = ((float4*)row)[v];
        float4 s = sv4[v];
        float4 b = b4[v];
        x.x = x.x * (s.x * 0.015625f) + b.x;
        x.y = x.y * (s.y * 0.015625f) + b.y;
        x.z = x.z * (s.z * 0.015625f) + b.z;
        x.w = x.w * (s.w * 0.015625f) + b.w;
        o4[v] = x;
    }
}

extern "C" void kernel_launch(void* const* d_in, const int* in_sizes, int n_in,
                              void* d_out, int out_size, void* d_ws, size_t ws_size,
                              hipStream_t stream) {
    const float* inp    = (const float*)d_in[0];
    const float* SU     = (const float*)d_in[1];
    const float* SV     = (const float*)d_in[2];
    const float* cb     = (const float*)d_in[3];
    const int*   Qidxs  = (const int*)d_in[4];
    const float* Wscale = (const float*)d_in[5];
    const float* bias   = (const float*)d_in[6];
    float* out = (float*)d_out;

    unsigned short* X  = (unsigned short*)d_ws;                                   // 64 MiB
    unsigned short* Wb = (unsigned short*)((char*)d_ws + (size_t)8192 * 4096 * 2); // 32 MiB

    hipLaunchKernelGGL(fwht_in_kernel, dim3(8192), dim3(256), 0, stream, inp, SU, Wscale, X);
    hipLaunchKernelGGL(decode_kernel,  dim3(4096), dim3(256), 0, stream, Qidxs, cb, Wb);
    hipLaunchKernelGGL(gemm_kernel,    dim3(2048), dim3(256), 0, stream, X, Wb, out);
    hipLaunchKernelGGL(fwht_out_kernel, dim3(8192), dim3(256), 0, stream, out, SV, bias);
}

// Round 2
// 612.436 us; speedup vs baseline: 1.1978x; 1.1978x over previous
//
#include <hip/hip_runtime.h>
#include <cstdint>

// QuIP#-style quantized linear on MI355X:
//   x = FWHT(input*SU) * Wscale/64  (bf16)
//   W = bf16(cb[Qidxs])             (bf16, [4096 out][4096 in], K-contiguous)
//   C = x @ W^T                     (256x256 8-phase counted-vmcnt MFMA GEMM)
//   out = FWHT(C)/64 * SV + bias    (in-place on d_out)

using bf16x8 = __attribute__((ext_vector_type(8))) __bf16;
using f32x4  = __attribute__((ext_vector_type(4))) float;

__device__ __forceinline__ unsigned short f2bf(float f) {
    unsigned int u = __float_as_uint(f);
    unsigned int r = (u + 0x7fffu + ((u >> 16) & 1u)) >> 16;
    return (unsigned short)r;
}

// ---------------- FWHT over 4096 floats in LDS, 256 threads ----------------
__device__ __forceinline__ void fwht4096(float* row, int t) {
    for (int h = 1; h < 4096; h <<= 1) {
#pragma unroll
        for (int q = 0; q < 8; ++q) {
            int p = t + (q << 8);
            int i = ((p & ~(h - 1)) << 1) | (p & (h - 1));
            float a = row[i];
            float b = row[i + h];
            row[i]     = a + b;
            row[i + h] = a - b;
        }
        __syncthreads();
    }
}

// ---------------- kernel 1: input scale + FWHT -> bf16 X ----------------
__global__ __launch_bounds__(256) void fwht_in_kernel(const float* __restrict__ inp,
                                                      const float* __restrict__ SU,
                                                      const float* __restrict__ wscale,
                                                      unsigned short* __restrict__ X) {
    __shared__ float row[4096];
    const int t = threadIdx.x;
    const size_t base = (size_t)blockIdx.x * 4096;
    const float4* in4 = (const float4*)(inp + base);
    const float4* su4 = (const float4*)SU;
#pragma unroll
    for (int j = 0; j < 4; ++j) {
        int v = t + (j << 8);
        float4 x = in4[v];
        float4 s = su4[v];
        x.x *= s.x; x.y *= s.y; x.z *= s.z; x.w *= s.w;
        ((float4*)row)[v] = x;
    }
    __syncthreads();
    fwht4096(row, t);
    const float sc = wscale[0] * 0.015625f;  // /sqrt(4096)
#pragma unroll
    for (int j = 0; j < 2; ++j) {
        int i0 = (t << 3) + (j << 11);
        union { unsigned short us[8]; uint4 v4; } pk;
#pragma unroll
        for (int c = 0; c < 8; ++c) pk.us[c] = f2bf(row[i0 + c] * sc);
        *(uint4*)(X + base + i0) = pk.v4;
    }
}

// ---------------- kernel 2: codebook decode -> bf16 W ----------------
__global__ __launch_bounds__(256) void decode_kernel(const int* __restrict__ Qidxs,
                                                     const float* __restrict__ cb,
                                                     unsigned short* __restrict__ Wb) {
    __shared__ float4 cbs[256];
    const int t = threadIdx.x;
    cbs[t] = ((const float4*)cb)[t];
    __syncthreads();
    const size_t o = blockIdx.x;
    const int* q = Qidxs + o * 1024;
    ushort4* wrow = (ushort4*)(Wb + o * 4096);
#pragma unroll
    for (int jj = 0; jj < 4; ++jj) {
        int j = t + (jj << 8);
        int idx = q[j];
        float4 v = cbs[idx];
        ushort4 w4;
        w4.x = f2bf(v.x); w4.y = f2bf(v.y); w4.z = f2bf(v.z); w4.w = f2bf(v.w);
        wrow[j] = w4;
    }
}

// ---------------- kernel 3: 256x256 8-phase bf16 GEMM C = X @ W^T ----------------
// X: [8192][4096] bf16, Wb: [4096][4096] bf16 (both K-contiguous), C: fp32.
// 8 waves (2Mx4N), BK=64, 2 K-tiles per loop iteration, 8 phases.
// LDS parts: [buf][half] of 128 rows x 64 k (16 KiB each); read-swizzle:
// physical 16B unit = logical unit ^ (row&7); global source pre-swizzled,
// global_load_lds destination linear (both-sides-or-neither rule).

__device__ __forceinline__ void stage_part(const unsigned short* __restrict__ src,
                                           int grow, int kt,
                                           unsigned short* dst, int tid) {
#pragma unroll
    for (int j = 0; j < 2; ++j) {
        int u = tid + j * 512;          // 16B unit index within part (0..1023)
        int r = u >> 3;                  // row 0..127
        int q = (u & 7) ^ (r & 7);       // logical k-unit for this physical slot
        const unsigned short* g = src + (size_t)(grow + r) * 4096 + kt + q * 8;
        __builtin_amdgcn_global_load_lds(
            (const __attribute__((address_space(1))) unsigned int*)g,
            (__attribute__((address_space(3))) unsigned int*)((char*)dst + u * 16),
            16, 0, 0);
    }
}

#define VM4 asm volatile("s_waitcnt vmcnt(4)" ::: "memory")
#define VM0 asm volatile("s_waitcnt vmcnt(0)" ::: "memory")

// Phase: ds-read quadrant frags -> issue one stage -> barrier -> MFMA x16 -> [vmcnt] -> barrier
#define PHASE(MQ, NQ, PA, PB, STAGE, VM) do {                                      \
    bf16x8 a0_[4], a1_[4], b0_[2], b1_[2];                                         \
    const char* pA_ = (const char*)(PA);                                           \
    const char* pB_ = (const char*)(PB);                                           \
    _Pragma("unroll")                                                              \
    for (int mf_ = 0; mf_ < 4; ++mf_) {                                            \
        a0_[mf_] = *(const bf16x8*)(pA_ + aRow + mf_ * 4096 + pu0);                \
        a1_[mf_] = *(const bf16x8*)(pA_ + aRow + mf_ * 4096 + pu1);                \
    }                                                                              \
    _Pragma("unroll")                                                              \
    for (int nf_ = 0; nf_ < 2; ++nf_) {                                            \
        b0_[nf_] = *(const bf16x8*)(pB_ + bRow + nf_ * 8192 + pu0);                \
        b1_[nf_] = *(const bf16x8*)(pB_ + bRow + nf_ * 8192 + pu1);                \
    }                                                                              \
    STAGE;                                                                         \
    __builtin_amdgcn_s_barrier();                                                  \
    __builtin_amdgcn_s_setprio(1);                                                 \
    _Pragma("unroll")                                                              \
    for (int mf_ = 0; mf_ < 4; ++mf_) {                                            \
        _Pragma("unroll")                                                          \
        for (int nf_ = 0; nf_ < 2; ++nf_) {                                        \
            acc[(MQ)*4 + mf_][(NQ)*2 + nf_] = __builtin_amdgcn_mfma_f32_16x16x32_bf16( \
                a0_[mf_], b0_[nf_], acc[(MQ)*4 + mf_][(NQ)*2 + nf_], 0, 0, 0);     \
            acc[(MQ)*4 + mf_][(NQ)*2 + nf_] = __builtin_amdgcn_mfma_f32_16x16x32_bf16( \
                a1_[mf_], b1_[nf_], acc[(MQ)*4 + mf_][(NQ)*2 + nf_], 0, 0, 0);     \
        }                                                                          \
    }                                                                              \
    __builtin_amdgcn_s_setprio(0);                                                 \
    VM;                                                                            \
    __builtin_amdgcn_s_barrier();                                                  \
} while (0)

__global__ __launch_bounds__(512, 2) void gemm8_kernel(const unsigned short* __restrict__ X,
                                                       const unsigned short* __restrict__ Wb,
                                                       float* __restrict__ C) {
    __shared__ unsigned short ldsA[2][2][8192];   // [buf][half][128*64]
    __shared__ unsigned short ldsB[2][2][8192];

    const int tid  = threadIdx.x;
    const int lane = tid & 63;
    const int w    = tid >> 6;   // 0..7
    const int wm   = w >> 2;     // 0..1
    const int wn   = w & 3;      // 0..3

    // XCD-aware block swizzle: 512 blocks = 8 XCDs x (8x8 tile region)
    const int bid   = blockIdx.x;
    const int xcd   = bid & 7;
    const int local = bid >> 3;
    const int tm = (xcd >> 1) * 8 + (local >> 3);   // 0..31
    const int tn = (xcd & 1) * 8 + (local & 7);     // 0..15
    const int brow = tm * 256;
    const int bcol = tn * 256;

    const int lr = lane & 15;
    const int lh = lane & 7;
    const int lg = lane >> 4;
    const int aRow = (wm * 16 + lr) * 128;   // byte offset of frag row within part
    const int bRow = (wn * 16 + lr) * 128;
    const int pu0 = (lg ^ lh) * 16;          // physical 16B unit for kk=0
    const int pu1 = ((4 + lg) ^ lh) * 16;    // kk=1

    f32x4 acc[8][4] = {};

    // Prologue: tile0 all parts + tile1 A0,B0; leave last 2 parts in flight.
    stage_part(X,  brow,       0,  &ldsA[0][0][0], tid);
    stage_part(Wb, bcol,       0,  &ldsB[0][0][0], tid);
    stage_part(Wb, bcol + 128, 0,  &ldsB[0][1][0], tid);
    stage_part(X,  brow + 128, 0,  &ldsA[0][1][0], tid);
    stage_part(X,  brow,       64, &ldsA[1][0][0], tid);
    stage_part(Wb, bcol,       64, &ldsB[1][0][0], tid);
    VM4;
    __builtin_amdgcn_s_barrier();

    // Main loop: iteration i computes tiles 2i (buf0) and 2i+1 (buf1),
    // stages B1/A1 of 2i+1, all of 2i+2, A0/B0 of 2i+3.
    for (int i = 0; i < 31; ++i) {
        const int kt1 = i * 128 + 64;
        const int ktA = i * 128 + 128;
        const int ktB = i * 128 + 192;
        PHASE(0, 0, &ldsA[0][0][0], &ldsB[0][0][0], stage_part(Wb, bcol + 128, kt1, &ldsB[1][1][0], tid), );
        PHASE(0, 1, &ldsA[0][0][0], &ldsB[0][1][0], stage_part(X,  brow + 128, kt1, &ldsA[1][1][0], tid), );
        PHASE(1, 0, &ldsA[0][1][0], &ldsB[0][0][0], stage_part(X,  brow,       ktA, &ldsA[0][0][0], tid), );
        PHASE(1, 1, &ldsA[0][1][0], &ldsB[0][1][0], stage_part(Wb, bcol,       ktA, &ldsB[0][0][0], tid), VM4);
        PHASE(0, 0, &ldsA[1][0][0], &ldsB[1][0][0], stage_part(Wb, bcol + 128, ktA, &ldsB[0][1][0], tid), );
        PHASE(0, 1, &ldsA[1][0][0], &ldsB[1][1][0], stage_part(X,  brow + 128, ktA, &ldsA[0][1][0], tid), );
        PHASE(1, 0, &ldsA[1][1][0], &ldsB[1][0][0], stage_part(X,  brow,       ktB, &ldsA[1][0][0], tid), );
        PHASE(1, 1, &ldsA[1][1][0], &ldsB[1][1][0], stage_part(Wb, bcol,       ktB, &ldsB[1][0][0], tid), VM4);
    }
    // Tail: tiles 62 (buf0) and 63 (buf1); finish staging tile 63, then drain.
    {
        const int kt1 = 4032;
        PHASE(0, 0, &ldsA[0][0][0], &ldsB[0][0][0], stage_part(Wb, bcol + 128, kt1, &ldsB[1][1][0], tid), );
        PHASE(0, 1, &ldsA[0][0][0], &ldsB[0][1][0], stage_part(X,  brow + 128, kt1, &ldsA[1][1][0], tid), );
        PHASE(1, 0, &ldsA[0][1][0], &ldsB[0][0][0], , );
        PHASE(1, 1, &ldsA[0][1][0], &ldsB[0][1][0], , VM0);
        PHASE(0, 0, &ldsA[1][0][0], &ldsB[1][0][0], , );
        PHASE(0, 1, &ldsA[1][0][0], &ldsB[1][1][0], , );
        PHASE(1, 0, &ldsA[1][1][0], &ldsB[1][0][0], , );
        PHASE(1, 1, &ldsA[1][1][0], &ldsB[1][1][0], , );
    }

    // Epilogue: C/D layout col=lane&15, row=(lane>>4)*4+reg; interleaved frags.
#pragma unroll
    for (int mf = 0; mf < 8; ++mf) {
        int row0 = brow + wm * 16 + mf * 32 + (lane >> 4) * 4;
#pragma unroll
        for (int nf = 0; nf < 4; ++nf) {
            int col = bcol + wn * 16 + nf * 64 + lr;
#pragma unroll
            for (int r = 0; r < 4; ++r)
                C[(size_t)(row0 + r) * 4096 + col] = acc[mf][nf][r];
        }
    }
}

// ---------------- kernel 4: output FWHT + SV scale + bias (in place) ----------------
__global__ __launch_bounds__(256) void fwht_out_kernel(float* __restrict__ out,
                                                       const float* __restrict__ SV,
                                                       const float* __restrict__ bias) {
    __shared__ float row[4096];
    const int t = threadIdx.x;
    const size_t base = (size_t)blockIdx.x * 4096;
    float4* o4 = (float4*)(out + base);
#pragma unroll
    for (int j = 0; j < 4; ++j) {
        int v = t + (j << 8);
        ((float4*)row)[v] = o4[v];
    }
    __syncthreads();
    fwht4096(row, t);
    const float4* sv4 = (const float4*)SV;
    const float4* b4  = (const float4*)bias;
#pragma unroll
    for (int j = 0; j < 4; ++j) {
        int v = t + (j << 8);
        float4 x = ((float4*)row)[v];
        float4 s = sv4[v];
        float4 b = b4[v];
        x.x = x.x * (s.x * 0.015625f) + b.x;
        x.y = x.y * (s.y * 0.015625f) + b.y;
        x.z = x.z * (s.z * 0.015625f) + b.z;
        x.w = x.w * (s.w * 0.015625f) + b.w;
        o4[v] = x;
    }
}

extern "C" void kernel_launch(void* const* d_in, const int* in_sizes, int n_in,
                              void* d_out, int out_size, void* d_ws, size_t ws_size,
                              hipStream_t stream) {
    const float* inp    = (const float*)d_in[0];
    const float* SU     = (const float*)d_in[1];
    const float* SV     = (const float*)d_in[2];
    const float* cb     = (const float*)d_in[3];
    const int*   Qidxs  = (const int*)d_in[4];
    const float* Wscale = (const float*)d_in[5];
    const float* bias   = (const float*)d_in[6];
    float* out = (float*)d_out;

    unsigned short* X  = (unsigned short*)d_ws;                                    // 64 MiB
    unsigned short* Wb = (unsigned short*)((char*)d_ws + (size_t)8192 * 4096 * 2); // 32 MiB

    hipLaunchKernelGGL(fwht_in_kernel, dim3(8192), dim3(256), 0, stream, inp, SU, Wscale, X);
    hipLaunchKernelGGL(decode_kernel,  dim3(4096), dim3(256), 0, stream, Qidxs, cb, Wb);
    hipLaunchKernelGGL(gemm8_kernel,   dim3(512),  dim3(512), 0, stream, X, Wb, out);
    hipLaunchKernelGGL(fwht_out_kernel, dim3(8192), dim3(256), 0, stream, out, SV, bias);
}

// Round 3
// 507.102 us; speedup vs baseline: 1.4466x; 1.2077x over previous
//
#include <hip/hip_runtime.h>
#include <cstdint>

// QuIP#-style quantized linear on MI355X:
//   x = FWHT(input*SU) * Wscale/64  (bf16)     [radix-16 FWHT, 3 barriers]
//   W = bf16(cb[Qidxs])             (bf16, K-contiguous)
//   C = x @ W^T                     (256x256 8-phase counted-vmcnt GEMM,
//                                    register-reused operand fragments)
//   out = FWHT(C)/64 * SV + bias    (radix-16, in-place on d_out)

using bf16x8 = __attribute__((ext_vector_type(8))) __bf16;
using f32x4  = __attribute__((ext_vector_type(4))) float;

__device__ __forceinline__ unsigned short f2bf(float f) {
    unsigned int u = __float_as_uint(f);
    unsigned int r = (u + 0x7fffu + ((u >> 16) & 1u)) >> 16;
    return (unsigned short)r;
}

// In-register 16-point WHT (natural order, matches reference butterflies).
__device__ __forceinline__ void h16(float v[16]) {
#pragma unroll
    for (int h = 1; h < 16; h <<= 1) {
#pragma unroll
        for (int g = 0; g < 16; g += (h << 1)) {
#pragma unroll
            for (int k = g; k < g + h; ++k) {
                float x = v[k], y = v[k + h];
                v[k] = x + y; v[k + h] = x - y;
            }
        }
    }
}

// LDS layout for 4096 = 16a x 16b x 16c floats:
//   phys(a,b,c) = a*256 + ((b^a)<<4) + (c^b)
// <=2-way bank conflict for: scatter-in, c-rows, b-strides, a-strides, pack-out.

// ---------------- kernel 1: input scale + FWHT -> bf16 X ----------------
__global__ __launch_bounds__(256) void fwht_in_kernel(const float* __restrict__ inp,
                                                      const float* __restrict__ SU,
                                                      const float* __restrict__ wscale,
                                                      unsigned short* __restrict__ X) {
    __shared__ float s[4096];
    const int t = threadIdx.x;
    const size_t base = (size_t)blockIdx.x * 4096;
    const float4* in4 = (const float4*)(inp + base);
    const float4* su4 = (const float4*)SU;
#pragma unroll
    for (int j = 0; j < 4; ++j) {
        const int v = t + (j << 8);
        float4 x = in4[v];
        float4 u = su4[v];
        x.x *= u.x; x.y *= u.y; x.z *= u.z; x.w *= u.w;
        const int a = v >> 6, b = (v >> 2) & 15, c0 = (v & 3) << 2;
        float* row = s + a * 256 + ((b ^ a) << 4);
        row[(c0 + 0) ^ b] = x.x; row[(c0 + 1) ^ b] = x.y;
        row[(c0 + 2) ^ b] = x.z; row[(c0 + 3) ^ b] = x.w;
    }
    __syncthreads();
    float v[16];
    {   // c-axis
        const int a = t >> 4, b = t & 15;
        float* row = s + a * 256 + ((b ^ a) << 4);
#pragma unroll
        for (int c = 0; c < 16; ++c) v[c] = row[c ^ b];
        h16(v);
#pragma unroll
        for (int c = 0; c < 16; ++c) row[c ^ b] = v[c];
    }
    __syncthreads();
    {   // b-axis
        const int a = t >> 4, c = t & 15;
#pragma unroll
        for (int b = 0; b < 16; ++b) v[b] = s[a * 256 + ((b ^ a) << 4) + (c ^ b)];
        h16(v);
#pragma unroll
        for (int b = 0; b < 16; ++b) s[a * 256 + ((b ^ a) << 4) + (c ^ b)] = v[b];
    }
    __syncthreads();
    {   // a-axis
        const int b = t >> 4, c = t & 15;
#pragma unroll
        for (int a = 0; a < 16; ++a) v[a] = s[a * 256 + ((b ^ a) << 4) + (c ^ b)];
        h16(v);
#pragma unroll
        for (int a = 0; a < 16; ++a) s[a * 256 + ((b ^ a) << 4) + (c ^ b)] = v[a];
    }
    __syncthreads();
    const float sc = wscale[0] * 0.015625f;  // /sqrt(4096)
#pragma unroll
    for (int p = 0; p < 2; ++p) {
        const int i0 = (p << 11) + (t << 3);
        const int a = i0 >> 8, b = (i0 >> 4) & 15, c0 = i0 & 15;
        const float* row = s + a * 256 + ((b ^ a) << 4);
        union { unsigned short us[8]; uint4 q; } pk;
#pragma unroll
        for (int z = 0; z < 8; ++z) pk.us[z] = f2bf(row[(c0 + z) ^ b] * sc);
        *(uint4*)(X + base + i0) = pk.q;
    }
}

// ---------------- kernel 2: codebook decode -> bf16 W ----------------
__global__ __launch_bounds__(256) void decode_kernel(const int* __restrict__ Qidxs,
                                                     const float* __restrict__ cb,
                                                     unsigned short* __restrict__ Wb) {
    __shared__ float4 cbs[256];
    const int t = threadIdx.x;
    cbs[t] = ((const float4*)cb)[t];
    __syncthreads();
    const size_t o = blockIdx.x;
    const int* q = Qidxs + o * 1024;
    ushort4* wrow = (ushort4*)(Wb + o * 4096);
#pragma unroll
    for (int jj = 0; jj < 4; ++jj) {
        int j = t + (jj << 8);
        int idx = q[j];
        float4 v = cbs[idx];
        ushort4 w4;
        w4.x = f2bf(v.x); w4.y = f2bf(v.y); w4.z = f2bf(v.z); w4.w = f2bf(v.w);
        wrow[j] = w4;
    }
}

// ---------------- kernel 3: 256x256 8-phase bf16 GEMM C = X @ W^T ----------------
// 8 waves (2Mx4N), BK=64, 2 K-tiles/iter, 8 phases, register-reused fragments:
// per K-tile phases read A0+B0 (12), B1 (4), A1 (8), none (0).
// LDS parts 128row x 64k, read-swizzle phys16Bunit = logical ^ (row&7);
// global source pre-swizzled, global_load_lds dest linear.

__device__ __forceinline__ void stage_part(const unsigned short* __restrict__ src,
                                           int grow, int kt,
                                           unsigned short* dst, int tid) {
#pragma unroll
    for (int j = 0; j < 2; ++j) {
        int u = tid + j * 512;
        int r = u >> 3;
        int q = (u & 7) ^ (r & 7);
        const unsigned short* g = src + (size_t)(grow + r) * 4096 + kt + q * 8;
        __builtin_amdgcn_global_load_lds(
            (const __attribute__((address_space(1))) unsigned int*)g,
            (__attribute__((address_space(3))) unsigned int*)((char*)dst + u * 16),
            16, 0, 0);
    }
}

#define VM4 asm volatile("s_waitcnt vmcnt(4)" ::: "memory")
#define VM0 asm volatile("s_waitcnt vmcnt(0)" ::: "memory")

#define RD_A(HOFF) do { _Pragma("unroll")                                          \
    for (int m_ = 0; m_ < 4; ++m_) {                                               \
        Ak0[m_] = *(const bf16x8*)(pA_ + (HOFF) + aRow + m_ * 4096 + pu0);         \
        Ak1[m_] = *(const bf16x8*)(pA_ + (HOFF) + aRow + m_ * 4096 + pu1);         \
    } } while (0)

#define RD_B(D0, D1, HOFF) do { _Pragma("unroll")                                  \
    for (int n_ = 0; n_ < 2; ++n_) {                                               \
        D0[n_] = *(const bf16x8*)(pB_ + (HOFF) + bRow + n_ * 8192 + pu0);          \
        D1[n_] = *(const bf16x8*)(pB_ + (HOFF) + bRow + n_ * 8192 + pu1);          \
    } } while (0)

#define MMQ(MQ, NQ, Bk0, Bk1) do {                                                 \
    __builtin_amdgcn_s_setprio(1);                                                 \
    _Pragma("unroll")                                                              \
    for (int m_ = 0; m_ < 4; ++m_) { _Pragma("unroll")                             \
        for (int n_ = 0; n_ < 2; ++n_) {                                           \
            acc[(MQ)*4+m_][(NQ)*2+n_] = __builtin_amdgcn_mfma_f32_16x16x32_bf16(   \
                Ak0[m_], Bk0[n_], acc[(MQ)*4+m_][(NQ)*2+n_], 0, 0, 0);             \
            acc[(MQ)*4+m_][(NQ)*2+n_] = __builtin_amdgcn_mfma_f32_16x16x32_bf16(   \
                Ak1[m_], Bk1[n_], acc[(MQ)*4+m_][(NQ)*2+n_], 0, 0, 0);             \
        } }                                                                        \
    __builtin_amdgcn_s_setprio(0); } while (0)

#define KTILE(PA, PB, ST1, ST2, ST3, ST4, VM_) do {                                \
    const char* pA_ = (const char*)(PA);                                           \
    const char* pB_ = (const char*)(PB);                                           \
    bf16x8 Ak0[4], Ak1[4], B0k0[2], B0k1[2], B1k0[2], B1k1[2];                     \
    RD_A(0); RD_B(B0k0, B0k1, 0); ST1; __builtin_amdgcn_s_barrier();               \
    MMQ(0, 0, B0k0, B0k1); __builtin_amdgcn_s_barrier();                           \
    RD_B(B1k0, B1k1, 16384); ST2; __builtin_amdgcn_s_barrier();                    \
    MMQ(0, 1, B1k0, B1k1); __builtin_amdgcn_s_barrier();                           \
    RD_A(16384); ST3; __builtin_amdgcn_s_barrier();                                \
    MMQ(1, 1, B1k0, B1k1); __builtin_amdgcn_s_barrier();                           \
    ST4; __builtin_amdgcn_s_barrier();                                             \
    MMQ(1, 0, B0k0, B0k1); VM_; __builtin_amdgcn_s_barrier();                      \
} while (0)

__global__ __launch_bounds__(512, 2) void gemm8_kernel(const unsigned short* __restrict__ X,
                                                       const unsigned short* __restrict__ Wb,
                                                       float* __restrict__ C) {
    __shared__ unsigned short ldsA[2][2][8192];   // [buf][half][128*64]
    __shared__ unsigned short ldsB[2][2][8192];

    const int tid  = threadIdx.x;
    const int lane = tid & 63;
    const int w    = tid >> 6;
    const int wm   = w >> 2;
    const int wn   = w & 3;

    const int bid   = blockIdx.x;
    const int xcd   = bid & 7;
    const int local = bid >> 3;
    const int tm = (xcd >> 1) * 8 + (local >> 3);
    const int tn = (xcd & 1) * 8 + (local & 7);
    const int brow = tm * 256;
    const int bcol = tn * 256;

    const int lr = lane & 15;
    const int lh = lane & 7;
    const int lg = lane >> 4;
    const int aRow = (wm * 16 + lr) * 128;
    const int bRow = (wn * 16 + lr) * 128;
    const int pu0 = (lg ^ lh) * 16;
    const int pu1 = ((4 + lg) ^ lh) * 16;

    f32x4 acc[8][4] = {};

    // Prologue: tile0 all 4 parts + tile1 first halves (left in flight).
    stage_part(X,  brow,       0,  &ldsA[0][0][0], tid);
    stage_part(Wb, bcol,       0,  &ldsB[0][0][0], tid);
    stage_part(Wb, bcol + 128, 0,  &ldsB[0][1][0], tid);
    stage_part(X,  brow + 128, 0,  &ldsA[0][1][0], tid);
    stage_part(X,  brow,       64, &ldsA[1][0][0], tid);
    stage_part(Wb, bcol,       64, &ldsB[1][0][0], tid);
    VM4;
    __builtin_amdgcn_s_barrier();

    for (int i = 0; i < 31; ++i) {
        const int kt1 = i * 128 + 64;
        const int ktA = i * 128 + 128;
        const int ktB = i * 128 + 192;
        KTILE(&ldsA[0][0][0], &ldsB[0][0][0],
              stage_part(Wb, bcol + 128, kt1, &ldsB[1][1][0], tid),
              stage_part(X,  brow + 128, kt1, &ldsA[1][1][0], tid),
              stage_part(X,  brow,       ktA, &ldsA[0][0][0], tid),
              stage_part(Wb, bcol,       ktA, &ldsB[0][0][0], tid), VM4);
        KTILE(&ldsA[1][0][0], &ldsB[1][0][0],
              stage_part(Wb, bcol + 128, ktA, &ldsB[0][1][0], tid),
              stage_part(X,  brow + 128, ktA, &ldsA[0][1][0], tid),
              stage_part(X,  brow,       ktB, &ldsA[1][0][0], tid),
              stage_part(Wb, bcol,       ktB, &ldsB[1][0][0], tid), VM4);
    }
    {   // Tail: tiles 62 (buf0) and 63 (buf1).
        const int kt1 = 31 * 128 + 64;  // 4032
        KTILE(&ldsA[0][0][0], &ldsB[0][0][0],
              stage_part(Wb, bcol + 128, kt1, &ldsB[1][1][0], tid),
              stage_part(X,  brow + 128, kt1, &ldsA[1][1][0], tid),
              , , VM0);
        KTILE(&ldsA[1][0][0], &ldsB[1][0][0], , , , , );
    }

    // Epilogue: C/D layout col=lane&15, row=(lane>>4)*4+reg; interleaved frags.
#pragma unroll
    for (int mf = 0; mf < 8; ++mf) {
        int row0 = brow + wm * 16 + mf * 32 + (lane >> 4) * 4;
#pragma unroll
        for (int nf = 0; nf < 4; ++nf) {
            int col = bcol + wn * 16 + nf * 64 + lr;
#pragma unroll
            for (int r = 0; r < 4; ++r)
                C[(size_t)(row0 + r) * 4096 + col] = acc[mf][nf][r];
        }
    }
}

// ---------------- kernel 4: output FWHT + SV scale + bias (in place) ----------------
__global__ __launch_bounds__(256) void fwht_out_kernel(float* __restrict__ out,
                                                       const float* __restrict__ SV,
                                                       const float* __restrict__ bias) {
    __shared__ float s[4096];
    const int t = threadIdx.x;
    const size_t base = (size_t)blockIdx.x * 4096;
    float4* o4 = (float4*)(out + base);
#pragma unroll
    for (int j = 0; j < 4; ++j) {
        const int v = t + (j << 8);
        float4 x = o4[v];
        const int a = v >> 6, b = (v >> 2) & 15, c0 = (v & 3) << 2;
        float* row = s + a * 256 + ((b ^ a) << 4);
        row[(c0 + 0) ^ b] = x.x; row[(c0 + 1) ^ b] = x.y;
        row[(c0 + 2) ^ b] = x.z; row[(c0 + 3) ^ b] = x.w;
    }
    __syncthreads();
    float v[16];
    {   // c-axis
        const int a = t >> 4, b = t & 15;
        float* row = s + a * 256 + ((b ^ a) << 4);
#pragma unroll
        for (int c = 0; c < 16; ++c) v[c] = row[c ^ b];
        h16(v);
#pragma unroll
        for (int c = 0; c < 16; ++c) row[c ^ b] = v[c];
    }
    __syncthreads();
    {   // b-axis
        const int a = t >> 4, c = t & 15;
#pragma unroll
        for (int b = 0; b < 16; ++b) v[b] = s[a * 256 + ((b ^ a) << 4) + (c ^ b)];
        h16(v);
#pragma unroll
        for (int b = 0; b < 16; ++b) s[a * 256 + ((b ^ a) << 4) + (c ^ b)] = v[b];
    }
    __syncthreads();
    {   // a-axis
        const int b = t >> 4, c = t & 15;
#pragma unroll
        for (int a = 0; a < 16; ++a) v[a] = s[a * 256 + ((b ^ a) << 4) + (c ^ b)];
        h16(v);
#pragma unroll
        for (int a = 0; a < 16; ++a) s[a * 256 + ((b ^ a) << 4) + (c ^ b)] = v[a];
    }
    __syncthreads();
    const float4* sv4 = (const float4*)SV;
    const float4* b4  = (const float4*)bias;
#pragma unroll
    for (int j = 0; j < 4; ++j) {
        const int vv = t + (j << 8);
        const int a = vv >> 6, b = (vv >> 2) & 15, c0 = (vv & 3) << 2;
        const float* row = s + a * 256 + ((b ^ a) << 4);
        float4 x;
        x.x = row[(c0 + 0) ^ b]; x.y = row[(c0 + 1) ^ b];
        x.z = row[(c0 + 2) ^ b]; x.w = row[(c0 + 3) ^ b];
        float4 sv = sv4[vv], bb = b4[vv];
        x.x = x.x * (sv.x * 0.015625f) + bb.x;
        x.y = x.y * (sv.y * 0.015625f) + bb.y;
        x.z = x.z * (sv.z * 0.015625f) + bb.z;
        x.w = x.w * (sv.w * 0.015625f) + bb.w;
        o4[vv] = x;
    }
}

extern "C" void kernel_launch(void* const* d_in, const int* in_sizes, int n_in,
                              void* d_out, int out_size, void* d_ws, size_t ws_size,
                              hipStream_t stream) {
    const float* inp    = (const float*)d_in[0];
    const float* SU     = (const float*)d_in[1];
    const float* SV     = (const float*)d_in[2];
    const float* cb     = (const float*)d_in[3];
    const int*   Qidxs  = (const int*)d_in[4];
    const float* Wscale = (const float*)d_in[5];
    const float* bias   = (const float*)d_in[6];
    float* out = (float*)d_out;

    unsigned short* X  = (unsigned short*)d_ws;                                    // 64 MiB
    unsigned short* Wb = (unsigned short*)((char*)d_ws + (size_t)8192 * 4096 * 2); // 32 MiB

    hipLaunchKernelGGL(fwht_in_kernel, dim3(8192), dim3(256), 0, stream, inp, SU, Wscale, X);
    hipLaunchKernelGGL(decode_kernel,  dim3(4096), dim3(256), 0, stream, Qidxs, cb, Wb);
    hipLaunchKernelGGL(gemm8_kernel,   dim3(512),  dim3(512), 0, stream, X, Wb, out);
    hipLaunchKernelGGL(fwht_out_kernel, dim3(8192), dim3(256), 0, stream, out, SV, bias);
}

// Round 7
// 497.498 us; speedup vs baseline: 1.4746x; 1.0193x over previous
//
#include <hip/hip_runtime.h>
#include <cstdint>

// QuIP#-style quantized linear on MI355X:
//   X  = FWHT(input*SU) * Wscale/64          (bf16, radix-16 FWHT)
//   W' = H * cb[Qidxs]     (fp32 FWHT over output dim fused w/ decode -> bf16)
//   out = (X @ W'^T) * SV/64 + bias          (proven 256x256 KTILE GEMM,
//                                             epilogue-fused scale+bias)
// Uses FWHT_o(X W^T) = X (H W)^T  (H symmetric) to delete the output-FWHT pass.
// This round: gemm deliberately kept at the round-3 HW-proven 2-barrier
// schedule; wfwht is the single new component (de-risking container failures).

using bf16x8 = __attribute__((ext_vector_type(8))) __bf16;
using f32x4  = __attribute__((ext_vector_type(4))) float;

__device__ __forceinline__ unsigned short f2bf(float f) {
    unsigned int u = __float_as_uint(f);
    unsigned int r = (u + 0x7fffu + ((u >> 16) & 1u)) >> 16;
    return (unsigned short)r;
}

// In-register 16-point WHT (natural order).
__device__ __forceinline__ void h16(float v[16]) {
#pragma unroll
    for (int h = 1; h < 16; h <<= 1) {
#pragma unroll
        for (int g = 0; g < 16; g += (h << 1)) {
#pragma unroll
            for (int k = g; k < g + h; ++k) {
                float x = v[k], y = v[k + h];
                v[k] = x + y; v[k + h] = x - y;
            }
        }
    }
}

// ---------------- kernel 1: input scale + FWHT -> bf16 X ----------------
// LDS layout 4096 = 16a x 16b x 16c: phys(a,b,c) = a*256 + ((b^a)<<4) + (c^b)
__global__ __launch_bounds__(256) void fwht_in_kernel(const float* __restrict__ inp,
                                                      const float* __restrict__ SU,
                                                      const float* __restrict__ wscale,
                                                      unsigned short* __restrict__ X) {
    __shared__ float s[4096];
    const int t = threadIdx.x;
    const size_t base = (size_t)blockIdx.x * 4096;
    const float4* in4 = (const float4*)(inp + base);
    const float4* su4 = (const float4*)SU;
#pragma unroll
    for (int j = 0; j < 4; ++j) {
        const int v = t + (j << 8);
        float4 x = in4[v];
        float4 u = su4[v];
        x.x *= u.x; x.y *= u.y; x.z *= u.z; x.w *= u.w;
        const int a = v >> 6, b = (v >> 2) & 15, c0 = (v & 3) << 2;
        float* row = s + a * 256 + ((b ^ a) << 4);
        row[(c0 + 0) ^ b] = x.x; row[(c0 + 1) ^ b] = x.y;
        row[(c0 + 2) ^ b] = x.z; row[(c0 + 3) ^ b] = x.w;
    }
    __syncthreads();
    float v[16];
    {   // c-axis
        const int a = t >> 4, b = t & 15;
        float* row = s + a * 256 + ((b ^ a) << 4);
#pragma unroll
        for (int c = 0; c < 16; ++c) v[c] = row[c ^ b];
        h16(v);
#pragma unroll
        for (int c = 0; c < 16; ++c) row[c ^ b] = v[c];
    }
    __syncthreads();
    {   // b-axis
        const int a = t >> 4, c = t & 15;
#pragma unroll
        for (int b = 0; b < 16; ++b) v[b] = s[a * 256 + ((b ^ a) << 4) + (c ^ b)];
        h16(v);
#pragma unroll
        for (int b = 0; b < 16; ++b) s[a * 256 + ((b ^ a) << 4) + (c ^ b)] = v[b];
    }
    __syncthreads();
    {   // a-axis
        const int b = t >> 4, c = t & 15;
#pragma unroll
        for (int a = 0; a < 16; ++a) v[a] = s[a * 256 + ((b ^ a) << 4) + (c ^ b)];
        h16(v);
#pragma unroll
        for (int a = 0; a < 16; ++a) s[a * 256 + ((b ^ a) << 4) + (c ^ b)] = v[a];
    }
    __syncthreads();
    const float sc = wscale[0] * 0.015625f;  // /sqrt(4096)
#pragma unroll
    for (int p = 0; p < 2; ++p) {
        const int i0 = (p << 11) + (t << 3);
        const int a = i0 >> 8, b = (i0 >> 4) & 15, c0 = i0 & 15;
        const float* row = s + a * 256 + ((b ^ a) << 4);
        union { unsigned short us[8]; uint4 q; } pk;
#pragma unroll
        for (int z = 0; z < 8; ++z) pk.us[z] = f2bf(row[(c0 + z) ^ b] * sc);
        *(uint4*)(X + base + i0) = pk.q;
    }
}

// ---------------- kernel 2: decode + FWHT over output dim -> bf16 W' ----------------
// Block handles an 8-column panel of W (cols p*8..p*8+7), all 4096 rows, fp32 in
// pitch-9 LDS (147 KB). Chunked panel->XCD map so adjacent panels share an L2.
__global__ __launch_bounds__(512) void wfwht_kernel(const int* __restrict__ Qidxs,
                                                    const float* __restrict__ cb,
                                                    unsigned short* __restrict__ Wp) {
    __shared__ float s[4096 * 9];
    __shared__ float4 cbs[256];
    const int t = threadIdx.x;
    const int bid = blockIdx.x;
    const int p = (bid & 7) * 64 + (bid >> 3);   // panel id 0..511
    if (t < 256) cbs[t] = ((const float4*)cb)[t];
    int idxs[16];
#pragma unroll
    for (int r = 0; r < 16; ++r) {
        int task = t + (r << 9);                 // 0..8191 = (o, j)
        int o = task >> 1, j = task & 1;
        idxs[r] = Qidxs[(size_t)o * 1024 + p * 2 + j];
    }
    __syncthreads();
#pragma unroll
    for (int r = 0; r < 16; ++r) {
        int task = t + (r << 9);
        int o = task >> 1, j = task & 1;
        float4 v4 = cbs[idxs[r]];
        float* row = s + o * 9 + j * 4;
        row[0] = v4.x; row[1] = v4.y; row[2] = v4.z; row[3] = v4.w;
    }
    __syncthreads();
    float v[16];
    // pass 1: butterfly over o&15 (stride 1 rows -> 9 floats)
#pragma unroll
    for (int r = 0; r < 4; ++r) {
        int tau = t + (r << 9);
        int c = tau & 7, b = (tau >> 3) & 15, a = tau >> 7;
        float* base = s + (a * 256 + b * 16) * 9 + c;
#pragma unroll
        for (int k = 0; k < 16; ++k) v[k] = base[k * 9];
        h16(v);
#pragma unroll
        for (int k = 0; k < 16; ++k) base[k * 9] = v[k];
    }
    __syncthreads();
    // pass 2: butterfly over (o>>4)&15 (stride 16 rows)
#pragma unroll
    for (int r = 0; r < 4; ++r) {
        int tau = t + (r << 9);
        int c = tau & 7, k = (tau >> 3) & 15, a = tau >> 7;
        float* base = s + (a * 256 + k) * 9 + c;
#pragma unroll
        for (int m = 0; m < 16; ++m) v[m] = base[m * 144];
        h16(v);
#pragma unroll
        for (int m = 0; m < 16; ++m) base[m * 144] = v[m];
    }
    __syncthreads();
    // pass 3: butterfly over o>>8 (stride 256 rows)
#pragma unroll
    for (int r = 0; r < 4; ++r) {
        int tau = t + (r << 9);
        int c = tau & 7, k = (tau >> 3) & 15, b = tau >> 7;
        float* base = s + (b * 16 + k) * 9 + c;
#pragma unroll
        for (int m = 0; m < 16; ++m) v[m] = base[m * 2304];
        h16(v);
#pragma unroll
        for (int m = 0; m < 16; ++m) base[m * 2304] = v[m];
    }
    __syncthreads();
    // pack out: 8 rows per thread, 16B stores (L2 assembles lines across panels)
#pragma unroll
    for (int r = 0; r < 8; ++r) {
        int o = t + (r << 9);
        const float* row = s + o * 9;
        union { unsigned short us[8]; uint4 q; } pk;
#pragma unroll
        for (int z = 0; z < 8; ++z) pk.us[z] = f2bf(row[z]);
        *(uint4*)(Wp + (size_t)o * 4096 + p * 8) = pk.q;
    }
}

// ---------------- kernel 3: 256x256 bf16 GEMM (round-3-proven KTILE schedule) ------
// out = (X @ W'^T) * SV/64 + bias.  8 waves (2Mx4N), BK=64, 2 K-tiles/iter,
// register-reused fragments; per K-tile phases read A0+B0 (12), B1 (4), A1 (8), none.
// LDS parts 128row x 64k, read-swizzle phys16Bunit = logical ^ (row&7);
// global source pre-swizzled, global_load_lds dest linear.

__device__ __forceinline__ void stage_part(const unsigned short* __restrict__ src,
                                           int grow, int kt,
                                           unsigned short* dst, int tid) {
#pragma unroll
    for (int j = 0; j < 2; ++j) {
        int u = tid + j * 512;
        int r = u >> 3;
        int q = (u & 7) ^ (r & 7);
        const unsigned short* g = src + (size_t)(grow + r) * 4096 + kt + q * 8;
        __builtin_amdgcn_global_load_lds(
            (const __attribute__((address_space(1))) unsigned int*)g,
            (__attribute__((address_space(3))) unsigned int*)((char*)dst + u * 16),
            16, 0, 0);
    }
}

#define VM4 asm volatile("s_waitcnt vmcnt(4)" ::: "memory")
#define VM0 asm volatile("s_waitcnt vmcnt(0)" ::: "memory")

#define RD_A(HOFF) do { _Pragma("unroll")                                          \
    for (int m_ = 0; m_ < 4; ++m_) {                                               \
        Ak0[m_] = *(const bf16x8*)(pA_ + (HOFF) + aRow + m_ * 4096 + pu0);         \
        Ak1[m_] = *(const bf16x8*)(pA_ + (HOFF) + aRow + m_ * 4096 + pu1);         \
    } } while (0)

#define RD_B(D0, D1, HOFF) do { _Pragma("unroll")                                  \
    for (int n_ = 0; n_ < 2; ++n_) {                                               \
        D0[n_] = *(const bf16x8*)(pB_ + (HOFF) + bRow + n_ * 8192 + pu0);          \
        D1[n_] = *(const bf16x8*)(pB_ + (HOFF) + bRow + n_ * 8192 + pu1);          \
    } } while (0)

#define MMQ(MQ, NQ, Bk0, Bk1) do {                                                 \
    __builtin_amdgcn_s_setprio(1);                                                 \
    _Pragma("unroll")                                                              \
    for (int m_ = 0; m_ < 4; ++m_) { _Pragma("unroll")                             \
        for (int n_ = 0; n_ < 2; ++n_) {                                           \
            acc[(MQ)*4+m_][(NQ)*2+n_] = __builtin_amdgcn_mfma_f32_16x16x32_bf16(   \
                Ak0[m_], Bk0[n_], acc[(MQ)*4+m_][(NQ)*2+n_], 0, 0, 0);             \
            acc[(MQ)*4+m_][(NQ)*2+n_] = __builtin_amdgcn_mfma_f32_16x16x32_bf16(   \
                Ak1[m_], Bk1[n_], acc[(MQ)*4+m_][(NQ)*2+n_], 0, 0, 0);             \
        } }                                                                        \
    __builtin_amdgcn_s_setprio(0); } while (0)

#define KTILE(PA, PB, ST1, ST2, ST3, ST4, VM_) do {                                \
    const char* pA_ = (const char*)(PA);                                           \
    const char* pB_ = (const char*)(PB);                                           \
    bf16x8 Ak0[4], Ak1[4], B0k0[2], B0k1[2], B1k0[2], B1k1[2];                     \
    RD_A(0); RD_B(B0k0, B0k1, 0); ST1; __builtin_amdgcn_s_barrier();               \
    MMQ(0, 0, B0k0, B0k1); __builtin_amdgcn_s_barrier();                           \
    RD_B(B1k0, B1k1, 16384); ST2; __builtin_amdgcn_s_barrier();                    \
    MMQ(0, 1, B1k0, B1k1); __builtin_amdgcn_s_barrier();                           \
    RD_A(16384); ST3; __builtin_amdgcn_s_barrier();                                \
    MMQ(1, 1, B1k0, B1k1); __builtin_amdgcn_s_barrier();                           \
    ST4; __builtin_amdgcn_s_barrier();                                             \
    MMQ(1, 0, B0k0, B0k1); VM_; __builtin_amdgcn_s_barrier();                      \
} while (0)

__global__ __launch_bounds__(512, 2) void gemm8_kernel(const unsigned short* __restrict__ X,
                                                       const unsigned short* __restrict__ Wb,
                                                       const float* __restrict__ SV,
                                                       const float* __restrict__ bias,
                                                       float* __restrict__ out) {
    __shared__ unsigned short ldsA[2][2][8192];   // [buf][half][128*64]
    __shared__ unsigned short ldsB[2][2][8192];

    const int tid  = threadIdx.x;
    const int lane = tid & 63;
    const int w    = tid >> 6;
    const int wm   = w >> 2;
    const int wn   = w & 3;

    const int bid   = blockIdx.x;
    const int xcd   = bid & 7;
    const int local = bid >> 3;
    const int tm = (xcd >> 1) * 8 + (local >> 3);
    const int tn = (xcd & 1) * 8 + (local & 7);
    const int brow = tm * 256;
    const int bcol = tn * 256;

    const int lr = lane & 15;
    const int lh = lane & 7;
    const int lg = lane >> 4;
    const int aRow = (wm * 16 + lr) * 128;
    const int bRow = (wn * 16 + lr) * 128;
    const int pu0 = (lg ^ lh) * 16;
    const int pu1 = ((4 + lg) ^ lh) * 16;

    f32x4 acc[8][4] = {};

    // Prologue: tile0 all 4 parts + tile1 first halves (left in flight).
    stage_part(X,  brow,       0,  &ldsA[0][0][0], tid);
    stage_part(Wb, bcol,       0,  &ldsB[0][0][0], tid);
    stage_part(Wb, bcol + 128, 0,  &ldsB[0][1][0], tid);
    stage_part(X,  brow + 128, 0,  &ldsA[0][1][0], tid);
    stage_part(X,  brow,       64, &ldsA[1][0][0], tid);
    stage_part(Wb, bcol,       64, &ldsB[1][0][0], tid);
    VM4;
    __builtin_amdgcn_s_barrier();

    for (int i = 0; i < 31; ++i) {
        const int kt1 = i * 128 + 64;
        const int ktA = i * 128 + 128;
        const int ktB = i * 128 + 192;
        KTILE(&ldsA[0][0][0], &ldsB[0][0][0],
              stage_part(Wb, bcol + 128, kt1, &ldsB[1][1][0], tid),
              stage_part(X,  brow + 128, kt1, &ldsA[1][1][0], tid),
              stage_part(X,  brow,       ktA, &ldsA[0][0][0], tid),
              stage_part(Wb, bcol,       ktA, &ldsB[0][0][0], tid), VM4);
        KTILE(&ldsA[1][0][0], &ldsB[1][0][0],
              stage_part(Wb, bcol + 128, ktA, &ldsB[0][1][0], tid),
              stage_part(X,  brow + 128, ktA, &ldsA[0][1][0], tid),
              stage_part(X,  brow,       ktB, &ldsA[1][0][0], tid),
              stage_part(Wb, bcol,       ktB, &ldsB[1][0][0], tid), VM4);
    }
    {   // Tail: tiles 62 (buf0) and 63 (buf1).
        const int kt1 = 31 * 128 + 64;  // 4032
        KTILE(&ldsA[0][0][0], &ldsB[0][0][0],
              stage_part(Wb, bcol + 128, kt1, &ldsB[1][1][0], tid),
              stage_part(X,  brow + 128, kt1, &ldsA[1][1][0], tid),
              , , VM0);
        KTILE(&ldsA[1][0][0], &ldsB[1][0][0], , , , , );
    }

    // Epilogue: fused SV/64 scale + bias; C/D layout col=lane&15, row=(lane>>4)*4+reg.
#pragma unroll
    for (int mf = 0; mf < 8; ++mf) {
        int row0 = brow + wm * 16 + mf * 32 + (lane >> 4) * 4;
#pragma unroll
        for (int nf = 0; nf < 4; ++nf) {
            int col = bcol + wn * 16 + nf * 64 + lr;
            float sv = SV[col] * 0.015625f;
            float bb = bias[col];
#pragma unroll
            for (int r = 0; r < 4; ++r)
                out[(size_t)(row0 + r) * 4096 + col] = acc[mf][nf][r] * sv + bb;
        }
    }
}

extern "C" void kernel_launch(void* const* d_in, const int* in_sizes, int n_in,
                              void* d_out, int out_size, void* d_ws, size_t ws_size,
                              hipStream_t stream) {
    const float* inp    = (const float*)d_in[0];
    const float* SU     = (const float*)d_in[1];
    const float* SV     = (const float*)d_in[2];
    const float* cb     = (const float*)d_in[3];
    const int*   Qidxs  = (const int*)d_in[4];
    const float* Wscale = (const float*)d_in[5];
    const float* bias   = (const float*)d_in[6];
    float* out = (float*)d_out;

    unsigned short* X  = (unsigned short*)d_ws;                                    // 64 MiB
    unsigned short* Wp = (unsigned short*)((char*)d_ws + (size_t)8192 * 4096 * 2); // 32 MiB

    hipLaunchKernelGGL(fwht_in_kernel, dim3(8192), dim3(256), 0, stream, inp, SU, Wscale, X);
    hipLaunchKernelGGL(wfwht_kernel,   dim3(512),  dim3(512), 0, stream, Qidxs, cb, Wp);
    hipLaunchKernelGGL(gemm8_kernel,   dim3(512),  dim3(512), 0, stream, X, Wp, SV, bias, out);
}